// Round 1
// baseline (451.176 us; speedup 1.0000x reference)
//
#include <hip/hip_runtime.h>

// Problem constants
#define Bn 256
#define Vn 512
#define Fn 256
// O = 2 hard-coded throughout.

// Workspace layout (bytes):
//   packed adjacency bits: [Bn*Vn][8] uint64  at 0        (8 MB)
//   dinv:                  [Bn*Vn] float      at 8388608   (512 KB)
//   Y = X@W:               [Bn*Vn] float2     at 8912896   (1 MB)
#define WS_PACKED_OFF 0
#define WS_DINV_OFF   8388608
#define WS_Y_OFF      8912896

// Kernel 1: read graphs ONCE; bit-pack rows + compute dinv = rsqrt(deg).
// One wave (64 lanes) per adjacency row of 512 int32.
__global__ __launch_bounds__(256) void pack_deg_kernel(
    const int* __restrict__ G,
    unsigned long long* __restrict__ P,
    float* __restrict__ dinv) {
  int gid  = blockIdx.x * 256 + threadIdx.x;
  int row  = gid >> 6;          // b*Vn + v, wave-uniform
  int lane = gid & 63;
  int v    = row & (Vn - 1);

  const int* r = G + (size_t)row * Vn;
  // 8 independent coalesced dword loads (256B each) for latency overlap
  int x0 = r[  0 + lane];
  int x1 = r[ 64 + lane];
  int x2 = r[128 + lane];
  int x3 = r[192 + lane];
  int x4 = r[256 + lane];
  int x5 = r[320 + lane];
  int x6 = r[384 + lane];
  int x7 = r[448 + lane];

  unsigned long long m0 = __ballot(x0 != 0);
  unsigned long long m1 = __ballot(x1 != 0);
  unsigned long long m2 = __ballot(x2 != 0);
  unsigned long long m3 = __ballot(x3 != 0);
  unsigned long long m4 = __ballot(x4 != 0);
  unsigned long long m5 = __ballot(x5 != 0);
  unsigned long long m6 = __ballot(x6 != 0);
  unsigned long long m7 = __ballot(x7 != 0);

  // Force self-loop bit (diag = 1). j is wave-uniform.
  int j = v >> 6;
  unsigned long long db = 1ull << (v & 63);
  if (j == 0) m0 |= db;
  else if (j == 1) m1 |= db;
  else if (j == 2) m2 |= db;
  else if (j == 3) m3 |= db;
  else if (j == 4) m4 |= db;
  else if (j == 5) m5 |= db;
  else if (j == 6) m6 |= db;
  else             m7 |= db;

  int deg = __popcll(m0) + __popcll(m1) + __popcll(m2) + __popcll(m3) +
            __popcll(m4) + __popcll(m5) + __popcll(m6) + __popcll(m7);

  // Lane i (i<8) stores word i: select via unrolled cndmask chain.
  unsigned long long sel = m0;
  sel = (lane == 1) ? m1 : sel;
  sel = (lane == 2) ? m2 : sel;
  sel = (lane == 3) ? m3 : sel;
  sel = (lane == 4) ? m4 : sel;
  sel = (lane == 5) ? m5 : sel;
  sel = (lane == 6) ? m6 : sel;
  sel = (lane == 7) ? m7 : sel;
  if (lane < 8) P[(size_t)row * 8 + lane] = sel;
  if (lane == 0) dinv[row] = rsqrtf((float)deg);
}

// Kernel 2: Y[b,v,:] = features[b,v,:] @ W  (W is [F,2] row-major).
// One wave per row; lane handles 4 consecutive features via float4.
__global__ __launch_bounds__(256) void xw_kernel(
    const float* __restrict__ X,
    const float* __restrict__ W,
    float2* __restrict__ Y) {
  int gid  = blockIdx.x * 256 + threadIdx.x;
  int row  = gid >> 6;
  int lane = gid & 63;

  const float4* xr = (const float4*)(X + (size_t)row * Fn);
  float4 x = xr[lane];
  const float4* wr = (const float4*)W;
  float4 w0 = wr[lane * 2];      // {W[4L][0],W[4L][1],W[4L+1][0],W[4L+1][1]}
  float4 w1 = wr[lane * 2 + 1];  // {W[4L+2][0],W[4L+2][1],W[4L+3][0],W[4L+3][1]}

  float s0 = x.x * w0.x + x.y * w0.z + x.z * w1.x + x.w * w1.z;
  float s1 = x.x * w0.y + x.y * w0.w + x.z * w1.y + x.w * w1.w;
  #pragma unroll
  for (int off = 32; off; off >>= 1) {
    s0 += __shfl_xor(s0, off);
    s1 += __shfl_xor(s1, off);
  }
  if (lane == 0) Y[row] = make_float2(s0, s1);
}

// Kernel 3: per-batch aggregation + bias + relu + head dot + sigmoid.
// One block per b. LDS holds Y[b,w,:]*dinv[b,w]. Each thread owns rows
// v and v+256 (shares the broadcast LDS read between them).
__global__ __launch_bounds__(256) void agg_head_kernel(
    const unsigned long long* __restrict__ P,
    const float* __restrict__ dinv,
    const float2* __restrict__ Y,
    const float* __restrict__ lw,
    const float* __restrict__ lb,
    const float* __restrict__ cb,
    float* __restrict__ out) {
  __shared__ float2 ylds[Vn];
  __shared__ float wsum[4];

  int b = blockIdx.x;
  int t = threadIdx.x;

  // Stage Y * dinv[w] (fold column normalization here)
  #pragma unroll
  for (int i = t; i < Vn; i += 256) {
    float  d = dinv[b * Vn + i];
    float2 y = Y[b * Vn + i];
    ylds[i] = make_float2(y.x * d, y.y * d);
  }
  __syncthreads();

  int v0 = t, v1 = t + 256;
  const unsigned long long* p0 = P + ((size_t)b * Vn + v0) * 8;
  const unsigned long long* p1 = P + ((size_t)b * Vn + v1) * 8;

  float a00 = 0.f, a01 = 0.f, a10 = 0.f, a11 = 0.f;
  for (int j = 0; j < 8; ++j) {
    unsigned long long m0 = p0[j];
    unsigned long long m1 = p1[j];
    const float2* yj = ylds + j * 64;
    #pragma unroll
    for (int k = 0; k < 64; ++k) {
      float2 y = yj[k];                       // wave-uniform broadcast read
      float s0 = (float)((m0 >> k) & 1ull);   // bfe + cvt
      float s1 = (float)((m1 >> k) & 1ull);
      a00 = fmaf(s0, y.x, a00);
      a01 = fmaf(s0, y.y, a01);
      a10 = fmaf(s1, y.x, a10);
      a11 = fmaf(s1, y.y, a11);
    }
  }

  float d0 = dinv[b * Vn + v0];
  float d1 = dinv[b * Vn + v1];
  float cb0 = cb[0], cb1 = cb[1];
  const float2* lw2 = (const float2*)lw;
  float2 w0v = lw2[v0];
  float2 w1v = lw2[v1];

  float h00 = fmaxf(fmaf(d0, a00, cb0), 0.f);
  float h01 = fmaxf(fmaf(d0, a01, cb1), 0.f);
  float h10 = fmaxf(fmaf(d1, a10, cb0), 0.f);
  float h11 = fmaxf(fmaf(d1, a11, cb1), 0.f);
  float c = h00 * w0v.x + h01 * w0v.y + h10 * w1v.x + h11 * w1v.y;

  #pragma unroll
  for (int off = 32; off; off >>= 1) c += __shfl_xor(c, off);
  if ((t & 63) == 0) wsum[t >> 6] = c;
  __syncthreads();
  if (t == 0) {
    float logit = wsum[0] + wsum[1] + wsum[2] + wsum[3] + lb[0];
    out[b] = 1.0f / (1.0f + expf(-logit));
  }
}

extern "C" void kernel_launch(void* const* d_in, const int* in_sizes, int n_in,
                              void* d_out, int out_size, void* d_ws, size_t ws_size,
                              hipStream_t stream) {
  const float* features = (const float*)d_in[0];
  const int*   graphs   = (const int*)d_in[1];
  const float* conv_w   = (const float*)d_in[2];
  const float* conv_b   = (const float*)d_in[3];
  const float* lin_w    = (const float*)d_in[4];
  const float* lin_b    = (const float*)d_in[5];
  float* out = (float*)d_out;

  char* ws = (char*)d_ws;
  unsigned long long* P = (unsigned long long*)(ws + WS_PACKED_OFF);
  float*  dinv = (float*)(ws + WS_DINV_OFF);
  float2* Y    = (float2*)(ws + WS_Y_OFF);

  // Kernel 1: 131072 rows, one wave each -> 32768 blocks of 256
  pack_deg_kernel<<<dim3(32768), dim3(256), 0, stream>>>(graphs, P, dinv);
  // Kernel 2: 131072 rows, one wave each
  xw_kernel<<<dim3(32768), dim3(256), 0, stream>>>(features, conv_w, Y);
  // Kernel 3: one block per batch element
  agg_head_kernel<<<dim3(Bn), dim3(256), 0, stream>>>(P, dinv, Y, lin_w, lin_b, conv_b, out);
}